// Round 2
// 289.838 us; speedup vs baseline: 1.0522x; 1.0522x over previous
//
#include <hip/hip_runtime.h>
#include <hip/hip_bf16.h>
#include <math.h>

// Head: B=8, T=4096, E=1024, H=64. out = softmax_causal(QK^T/8) V, fp32 out.
// R7: split-K attention (R6 design) + ws_size guard. Fixed-reference softmax
// (p=2^s, no running max) makes key-splits additive, so blocks = (b,jq,split)
// with S(jq)=jq/16+1 -> 1280 near-uniform blocks (8..17 iters) vs 512 paired
// blocks where the light half drained early (Occupancy was 11%). Partial
// (o,l) fp32 in ws; comb_kernel sums <=4 slots + normalizes. If ws_size is
// too small for partials, fall back to the R5 direct schedule (verified).
// Q pre-scaled by 0.125*log2e in proj so attn uses exp2f (bare v_exp_f32);
// pk2 = v_cvt_pk_bf16_f32.

#define BB 8
#define TT 4096
#define EE 1024
#define HH 64
#define NSLOT 160   // split-chunks per batch: sum_{jq<64} (jq/16+1)
#define SLOTF 4160  // floats per partial slot: 64*64 o + 64 l

typedef __attribute__((ext_vector_type(8))) short short8;
typedef __attribute__((ext_vector_type(4))) float floatx4;
typedef short8 __attribute__((may_alias)) short8_a;
typedef uint2 __attribute__((may_alias)) uint2_a;
typedef uint4 __attribute__((may_alias)) uint4_a;
typedef float4 __attribute__((may_alias)) float4_a;

#define GLDS(gp, lp)                                                     \
  __builtin_amdgcn_global_load_lds(                                      \
      (const __attribute__((address_space(1))) unsigned int*)(gp),       \
      (__attribute__((address_space(3))) unsigned int*)(lp), 16, 0, 0)

__device__ __forceinline__ unsigned short f2bf(float f) {
  union { float f; unsigned int u; } v; v.f = f;
  unsigned int r = v.u + 0x7fffu + ((v.u >> 16) & 1u);  // RNE
  return (unsigned short)(r >> 16);
}
__device__ __forceinline__ unsigned int pk2(float a, float b) {
  unsigned int r;
  asm("v_cvt_pk_bf16_f32 %0, %1, %2" : "=v"(r) : "v"(a), "v"(b));
  return r;
}
__device__ __forceinline__ floatx4 fzero() {
  floatx4 z = {0.f, 0.f, 0.f, 0.f};
  return z;
}
__device__ __forceinline__ floatx4 mfma_bf16(short8 a, short8 b, floatx4 c) {
  return __builtin_amdgcn_mfma_f32_16x16x32_bf16(a, b, c, 0, 0, 0);
}
__device__ __forceinline__ short8 pack8(float4 a, float4 b) {
  union { unsigned int u[4]; short8 s; } r;
  r.u[0] = pk2(a.x, a.y);
  r.u[1] = pk2(a.z, a.w);
  r.u[2] = pk2(b.x, b.y);
  r.u[3] = pk2(b.z, b.w);
  return r.s;
}

// ---------------------------------------------------------------------------
// Kernel 1: W[e][h] fp32 -> wt3[m][h][e] bf16 (m=0:K,1:Q,2:V). 48 blocks.
// ---------------------------------------------------------------------------
__global__ __launch_bounds__(256) void wt_kernel(
    const float* __restrict__ Wk, const float* __restrict__ Wq,
    const float* __restrict__ Wv, unsigned short* __restrict__ wt3) {
  __shared__ float tile[64][65];
  const int m = blockIdx.y;
  const int eb = blockIdx.x;  // e-block of 64
  const float* W = (m == 0) ? Wk : ((m == 1) ? Wq : Wv);
  const int t = threadIdx.x;
  {
    const int r = t >> 2;            // e-local
    const int c0 = (t & 3) * 16;     // h
    const float* src = W + (size_t)(eb * 64 + r) * 64 + c0;
#pragma unroll
    for (int i = 0; i < 16; ++i) tile[r][c0 + i] = src[i];
  }
  __syncthreads();
  {
    const int h = t >> 2;
    const int e0 = (t & 3) * 16;
    unsigned int w[8];
#pragma unroll
    for (int i = 0; i < 8; ++i)
      w[i] = pk2(tile[e0 + 2 * i][h], tile[e0 + 2 * i + 1][h]);
    unsigned short* dst = wt3 + (size_t)(m * 64 + h) * EE + eb * 64 + e0;
    ((uint4_a*)dst)[0] = make_uint4(w[0], w[1], w[2], w[3]);
    ((uint4_a*)(dst + 8))[0] = make_uint4(w[4], w[5], w[6], w[7]);
  }
}

// ---------------------------------------------------------------------------
// Kernel 2: projections. 512 blocks x 256 thr; block = 64 rows x 192 cols.
// B-panel staged once per block per chunk via global_load_lds (frag-contig
// LDS dbuf); A direct-to-reg prefetch. Q pre-scaled by 0.125*log2(e) so the
// attention kernel can use exp2 (bare v_exp_f32) instead of expf.
// ---------------------------------------------------------------------------
__global__ __launch_bounds__(256) void proj_kernel(
    const float* __restrict__ x, const unsigned short* __restrict__ wt3,
    unsigned short* __restrict__ kws, unsigned short* __restrict__ qws,
    unsigned short* __restrict__ vtws) {
  __shared__ unsigned short Bl[2][24][512];  // [buf][fragidx=j*2+f][1KB frag]
  const int t = threadIdx.x;
  const int wv = t >> 6, lane = t & 63;
  const int l16 = lane & 15, quad = lane >> 4;
  const int mshalf = wv & 1;        // row half (32 rows)
  const int jbase = (wv >> 1) * 6;  // col-tile group (6 of 12)
  const size_t row0 = (size_t)blockIdx.x * 64;

  floatx4 acc[6][2];
#pragma unroll
  for (int j = 0; j < 6; ++j)
#pragma unroll
    for (int m2 = 0; m2 < 2; ++m2) acc[j][m2] = fzero();

  const float* xbase = x + (row0 + mshalf * 32 + l16) * EE + quad * 8;

  float4 ra[2][2][2], rb[2][2][2];  // [m2][f][g]
#pragma unroll
  for (int m2 = 0; m2 < 2; ++m2)
#pragma unroll
    for (int f = 0; f < 2; ++f)
#pragma unroll
      for (int g = 0; g < 2; ++g)
        ra[m2][f][g] = *(const float4_a*)(xbase + (size_t)m2 * 16 * EE + f * 32 + g * 4);

#define STAGE_B(buf, kc)                                                       \
  {                                                                            \
    _Pragma("unroll") for (int i = 0; i < 6; ++i) {                            \
      const int idx = wv * 6 + i;                                              \
      const int j = idx >> 1, f = idx & 1;                                     \
      const unsigned short* gp =                                               \
          wt3 + (size_t)(j * 16 + l16) * EE + (kc) + f * 32 + quad * 8;        \
      GLDS(gp, &Bl[buf][idx][0]);                                              \
    }                                                                          \
  }

  STAGE_B(0, 0);
  __syncthreads();

  for (int c = 0; c < 16; ++c) {
    const int cur = c & 1;
    if (c < 15) {
      STAGE_B(cur ^ 1, (c + 1) * 64);
#pragma unroll
      for (int m2 = 0; m2 < 2; ++m2)
#pragma unroll
        for (int f = 0; f < 2; ++f)
#pragma unroll
          for (int g = 0; g < 2; ++g)
            rb[m2][f][g] = *(const float4_a*)(xbase + (size_t)m2 * 16 * EE +
                                              (c + 1) * 64 + f * 32 + g * 4);
    }
    short8 af[2][2];
#pragma unroll
    for (int m2 = 0; m2 < 2; ++m2)
#pragma unroll
      for (int f = 0; f < 2; ++f) af[m2][f] = pack8(ra[m2][f][0], ra[m2][f][1]);
#pragma unroll
    for (int j = 0; j < 6; ++j)
#pragma unroll
      for (int f = 0; f < 2; ++f) {
        short8 bf = *(const short8_a*)&Bl[cur][(jbase + j) * 2 + f][lane * 8];
#pragma unroll
        for (int m2 = 0; m2 < 2; ++m2)
          acc[j][m2] = mfma_bf16(af[m2][f], bf, acc[j][m2]);
      }
#pragma unroll
    for (int m2 = 0; m2 < 2; ++m2)
#pragma unroll
      for (int f = 0; f < 2; ++f)
#pragma unroll
        for (int g = 0; g < 2; ++g) ra[m2][f][g] = rb[m2][f][g];
    __syncthreads();
  }
#undef STAGE_B

  const int b = (int)(row0 >> 12);
  const int tt0 = (int)(row0 & (TT - 1));
#pragma unroll
  for (int j = 0; j < 6; ++j) {
    const int jg = jbase + j;
    const int m = jg >> 2;
    const int h0 = (jg & 3) * 16;
#pragma unroll
    for (int m2 = 0; m2 < 2; ++m2) {
      floatx4 a = acc[j][m2];
      const int rbase = mshalf * 32 + m2 * 16 + quad * 4;
      if (m == 0) {
#pragma unroll
        for (int r = 0; r < 4; ++r)
          kws[(row0 + rbase + r) * HH + h0 + l16] = f2bf(a[r]);
      } else if (m == 1) {
        // 0.125 (1/sqrt(H)) * log2(e): attn does p = 2^s
#pragma unroll
        for (int r = 0; r < 4; ++r)
          qws[(row0 + rbase + r) * HH + h0 + l16] = f2bf(a[r] * 0.18033688011112042f);
      } else {  // v transposed [B,64,T]
        uint2 p;
        p.x = pk2(a[0], a[1]);
        p.y = pk2(a[2], a[3]);
        ((uint2_a*)&vtws[(size_t)(b * 64 + h0 + l16) * TT + tt0 + rbase])[0] = p;
      }
    }
  }
}

// ---------------------------------------------------------------------------
// Kernel 3: flash attention. Templated:
//  SPLIT=1: block=(b,jq,split); cid in [0,160) enumerates (jq,s), S(jq)=
//    jq/16+1 splits of key-tile range [0,jq]; 8..17 iters/block, 1280 blocks.
//    Writes partial fp32 (o,l) to slot blockIdx.x; comb_kernel finishes.
//  SPLIT=0 (ws fallback, == verified R5): 512 blocks, paired jq mapping,
//    full key range, in-kernel normalize, direct out write.
// Fixed-reference softmax: p = 2^s (q pre-scaled by 0.125*log2e), masked
// lanes 2^(-1e30) = 0. id = b + 8*cid keeps batch b on XCD b (L2 locality).
// ---------------------------------------------------------------------------
template <bool SPLIT>
__global__ __launch_bounds__(256) void attn_kernel(
    const unsigned short* __restrict__ kws, const unsigned short* __restrict__ qws,
    const unsigned short* __restrict__ vtws, float* __restrict__ dst) {
  __shared__ unsigned short KV[2][16][512];  // 32 KB dbuf
  __shared__ unsigned short pb[4][16][72];   // per-wave P, +8 pad
  const int t = threadIdx.x;
  const int wv = t >> 6, lane = t & 63;
  const int l16 = lane & 15, quad = lane >> 4;
  const int id = (int)blockIdx.x;
  int b, jq, kt0, kt1;
  if (SPLIT) {
    b = id & 7;
    const int cid = id >> 3;  // 0..159
    int s, S;
    if (cid < 16) {
      jq = cid; s = 0; S = 1;
    } else if (cid < 48) {
      const int u = cid - 16; jq = 16 + (u >> 1); s = u & 1; S = 2;
    } else if (cid < 96) {
      const int u = cid - 48; const int d = u / 3; jq = 32 + d; s = u - 3 * d; S = 3;
    } else {
      const int u = cid - 96; jq = 48 + (u >> 2); s = u & 3; S = 4;
    }
    const int n = jq + 1;
    kt0 = (s * n) / S;
    kt1 = ((s + 1) * n) / S;
  } else {
    const int r255 = id & 255;
    b = r255 & 7;
    const int m = r255 >> 3;  // 0..31
    jq = (id < 256) ? m : 63 - m;
    kt0 = 0;
    kt1 = jq + 1;
  }
  const int q0 = jq * 64;
  const int qrow = q0 + wv * 16 + l16;

  const unsigned short* qp = qws + ((size_t)b * TT + qrow) * HH + quad * 8;
  short8 qa0 = *(const short8_a*)(qp);
  short8 qa1 = *(const short8_a*)(qp + 32);

  floatx4 o[4];
#pragma unroll
  for (int nt = 0; nt < 4; ++nt) o[nt] = fzero();
  float lsum = 0.f;

#define STAGE_KV(buf, ks)                                                      \
  {                                                                            \
    _Pragma("unroll") for (int i = 0; i < 4; ++i) {                            \
      const int idx = wv * 4 + i;                                              \
      const unsigned short* gp;                                                \
      if (idx < 8) {                                                           \
        const int nt = idx >> 1, f = idx & 1;                                  \
        gp = kws + ((size_t)b * TT + (ks) + nt * 16 + l16) * HH + f * 32 +     \
             quad * 8;                                                         \
      } else {                                                                 \
        const int nt = (idx - 8) >> 1, f = idx & 1;                            \
        gp = vtws + ((size_t)(b * 64 + nt * 16 + l16)) * TT + (ks) + f * 32 +  \
             quad * 8;                                                         \
      }                                                                        \
      GLDS(gp, &KV[buf][idx][0]);                                              \
    }                                                                          \
  }

  STAGE_KV(0, kt0 * 64);
  __syncthreads();

  for (int kt = kt0; kt < kt1; ++kt) {
    const int cur = (kt - kt0) & 1;
    const int ks = kt * 64;
    if (kt + 1 < kt1) STAGE_KV(cur ^ 1, ks + 64);

    floatx4 sc[4];
#pragma unroll
    for (int nt = 0; nt < 4; ++nt) {
      short8 kf0 = *(const short8_a*)&KV[cur][nt * 2][lane * 8];
      short8 kf1 = *(const short8_a*)&KV[cur][nt * 2 + 1][lane * 8];
      floatx4 z = fzero();
      z = mfma_bf16(kf0, qa0, z);
      z = mfma_bf16(kf1, qa1, z);
      sc[nt] = z;
    }
    if (kt == jq) {  // causal mask on diagonal tile -> exp2 gives exact 0
#pragma unroll
      for (int nt = 0; nt < 4; ++nt)
#pragma unroll
        for (int r = 0; r < 4; ++r) {
          const int key = ks + nt * 16 + quad * 4 + r;
          if (key > qrow) sc[nt][r] = -1e30f;
        }
    }
    // fixed-reference softmax: p = 2^s (s already in log2 domain)
#pragma unroll
    for (int nt = 0; nt < 4; ++nt) {
      const float p0 = exp2f(sc[nt][0]);
      const float p1 = exp2f(sc[nt][1]);
      const float p2 = exp2f(sc[nt][2]);
      const float p3 = exp2f(sc[nt][3]);
      lsum += (p0 + p1) + (p2 + p3);
      uint2 pw;
      pw.x = pk2(p0, p1);
      pw.y = pk2(p2, p3);
      ((uint2_a*)&pb[wv][l16][nt * 16 + quad * 4])[0] = pw;
    }
    // P frags (same-wave LDS RAW; lgkmcnt handles)
    short8 pf0 = *(const short8_a*)&pb[wv][l16][quad * 8];
    short8 pf1 = *(const short8_a*)&pb[wv][l16][quad * 8 + 32];
#pragma unroll
    for (int nt = 0; nt < 4; ++nt) {
      short8 vf0 = *(const short8_a*)&KV[cur][8 + nt * 2][lane * 8];
      short8 vf1 = *(const short8_a*)&KV[cur][8 + nt * 2 + 1][lane * 8];
      o[nt] = mfma_bf16(vf0, pf0, o[nt]);
      o[nt] = mfma_bf16(vf1, pf1, o[nt]);
    }
    __syncthreads();
  }
#undef STAGE_KV

  // l over the 4 quads of this query column
  float lr = lsum;
  lr += __shfl_xor(lr, 16);
  lr += __shfl_xor(lr, 32);

  if (SPLIT) {
    float* op = dst + (size_t)id * SLOTF;
    const int ql = wv * 16 + l16;
#pragma unroll
    for (int nt = 0; nt < 4; ++nt) {
      float4 st;
      st.x = o[nt][0];
      st.y = o[nt][1];
      st.z = o[nt][2];
      st.w = o[nt][3];
      *(float4_a*)&op[(size_t)ql * 64 + nt * 16 + quad * 4] = st;
    }
    if (lane < 16) op[4096 + wv * 16 + lane] = lr;
  } else {
    const float inv = 1.0f / lr;
#pragma unroll
    for (int nt = 0; nt < 4; ++nt) {
      float4 st;
      st.x = o[nt][0] * inv;
      st.y = o[nt][1] * inv;
      st.z = o[nt][2] * inv;
      st.w = o[nt][3] * inv;
      *(float4_a*)&dst[((size_t)b * TT + qrow) * HH + nt * 16 + quad * 4] = st;
    }
  }
}

// ---------------------------------------------------------------------------
// Kernel 4 (split path): combine partials. 512 blocks = (b, jq); sums S(jq)
// slots of (o, l), writes out = o_sum / l_sum. Slots written by same-b attn
// blocks live on the same XCD (id = b mod 8) -> mostly L2 reads.
// ---------------------------------------------------------------------------
__global__ __launch_bounds__(256) void comb_kernel(
    const float* __restrict__ part, float* __restrict__ out) {
  const int id = (int)blockIdx.x;
  const int b = id & 7;
  const int jq = id >> 3;  // 0..63
  const int tq = jq >> 4;
  const int S = tq + 1;
  const int P = 8 * tq * (tq + 1) + (jq & 15) * S;  // prefix of (jq,0) in cid space
  const int t = threadIdx.x;
  const int r0 = t >> 6;   // 0..3
  const int h = t & 63;
  const float* s0 = part + (size_t)(b + 8 * P) * SLOTF;
  const size_t sstr = (size_t)8 * SLOTF;  // slot stride between consecutive s

#pragma unroll 4
  for (int i = 0; i < 16; ++i) {
    const int r = i * 4 + r0;
    float acc = 0.f, l = 0.f;
    for (int s2 = 0; s2 < S; ++s2) {
      acc += s0[(size_t)s2 * sstr + (size_t)r * 64 + h];
      l += s0[(size_t)s2 * sstr + 4096 + r];
    }
    out[((size_t)b * TT + jq * 64 + r) * HH + h] = acc / l;
  }
}

// ---------------------------------------------------------------------------
extern "C" void kernel_launch(void* const* d_in, const int* in_sizes, int n_in,
                              void* d_out, int out_size, void* d_ws, size_t ws_size,
                              hipStream_t stream) {
  const float* x = (const float*)d_in[0];
  const float* Wk = (const float*)d_in[1];
  const float* Wq = (const float*)d_in[2];
  const float* Wv = (const float*)d_in[3];
  float* out = (float*)d_out;

  // ws layout: k bf16 [B,T,64] | q bf16 [B,T,64] | vT bf16 [B,64,T] |
  //            wt3 bf16 [3,64,1024] | partials fp32 [1280][4160] (if room)
  unsigned short* kws = (unsigned short*)d_ws;
  unsigned short* qws = kws + (size_t)BB * TT * HH;
  unsigned short* vtws = qws + (size_t)BB * TT * HH;
  unsigned short* wt3 = vtws + (size_t)BB * TT * HH;
  float* part = (float*)(wt3 + (size_t)3 * HH * EE);

  const size_t base_bytes = (size_t)3 * BB * TT * HH * 2 + (size_t)3 * HH * EE * 2;
  const size_t need = base_bytes + (size_t)BB * NSLOT * SLOTF * 4;
  const bool use_split = (ws_size >= need);

  hipLaunchKernelGGL(wt_kernel, dim3(16, 3), dim3(256), 0, stream, Wk, Wq, Wv, wt3);
  hipLaunchKernelGGL(proj_kernel, dim3(512), dim3(256), 0, stream, x, wt3, kws, qws,
                     vtws);
  if (use_split) {
    hipLaunchKernelGGL((attn_kernel<true>), dim3(BB * NSLOT), dim3(256), 0, stream,
                       kws, qws, vtws, part);
    hipLaunchKernelGGL(comb_kernel, dim3(512), dim3(256), 0, stream, part, out);
  } else {
    hipLaunchKernelGGL((attn_kernel<false>), dim3(512), dim3(256), 0, stream,
                       kws, qws, vtws, out);
  }
}

// Round 4
// 283.335 us; speedup vs baseline: 1.0764x; 1.0229x over previous
//
#include <hip/hip_runtime.h>
#include <hip/hip_bf16.h>
#include <math.h>

// Head: B=8, T=4096, E=1024, H=64. out = softmax_causal(QK^T/8) V, fp32 out.
// R9 == R8 resubmit (R8 hit "container failed twice" -- same infra signature
// as R1, whose code then passed verbatim in R2; audit found no hang/OOB in
// the new proj pipeline, so treating as flake).
// R8: proj rewritten to the m201-style counted-vmcnt pipeline: ALL global
// traffic via global_load_lds (A fp32 staged too, XOR-swizzled via
// pre-swizzled source), triple-buffered 20KB chunks (k=32), raw s_barrier +
// s_waitcnt vmcnt(5) (never 0 in steady state) so stage(c+1) stays in
// flight across two compute phases. Old structure drained vmcnt(0) at every
// __syncthreads -> one serialized HBM round trip per chunk (proj 80us,
// all counters idle). attn split-K + comb + wt unchanged from passing R7.

#define BB 8
#define TT 4096
#define EE 1024
#define HH 64
#define NSLOT 160   // split-chunks per batch: sum_{jq<64} (jq/16+1)
#define SLOTF 4160  // floats per partial slot: 64*64 o + 64 l

typedef __attribute__((ext_vector_type(8))) short short8;
typedef __attribute__((ext_vector_type(4))) float floatx4;
typedef short8 __attribute__((may_alias)) short8_a;
typedef uint2 __attribute__((may_alias)) uint2_a;
typedef uint4 __attribute__((may_alias)) uint4_a;
typedef float4 __attribute__((may_alias)) float4_a;

#define GLDS(gp, lp)                                                     \
  __builtin_amdgcn_global_load_lds(                                      \
      (const __attribute__((address_space(1))) unsigned int*)(gp),       \
      (__attribute__((address_space(3))) unsigned int*)(lp), 16, 0, 0)

__device__ __forceinline__ unsigned short f2bf(float f) {
  union { float f; unsigned int u; } v; v.f = f;
  unsigned int r = v.u + 0x7fffu + ((v.u >> 16) & 1u);  // RNE
  return (unsigned short)(r >> 16);
}
__device__ __forceinline__ unsigned int pk2(float a, float b) {
  unsigned int r;
  asm("v_cvt_pk_bf16_f32 %0, %1, %2" : "=v"(r) : "v"(a), "v"(b));
  return r;
}
__device__ __forceinline__ floatx4 fzero() {
  floatx4 z = {0.f, 0.f, 0.f, 0.f};
  return z;
}
__device__ __forceinline__ floatx4 mfma_bf16(short8 a, short8 b, floatx4 c) {
  return __builtin_amdgcn_mfma_f32_16x16x32_bf16(a, b, c, 0, 0, 0);
}
__device__ __forceinline__ short8 pack8(float4 a, float4 b) {
  union { unsigned int u[4]; short8 s; } r;
  r.u[0] = pk2(a.x, a.y);
  r.u[1] = pk2(a.z, a.w);
  r.u[2] = pk2(b.x, b.y);
  r.u[3] = pk2(b.z, b.w);
  return r.s;
}

// ---------------------------------------------------------------------------
// Kernel 1: W[e][h] fp32 -> wt3[m][h][e] bf16 (m=0:K,1:Q,2:V). 48 blocks.
// ---------------------------------------------------------------------------
__global__ __launch_bounds__(256) void wt_kernel(
    const float* __restrict__ Wk, const float* __restrict__ Wq,
    const float* __restrict__ Wv, unsigned short* __restrict__ wt3) {
  __shared__ float tile[64][65];
  const int m = blockIdx.y;
  const int eb = blockIdx.x;  // e-block of 64
  const float* W = (m == 0) ? Wk : ((m == 1) ? Wq : Wv);
  const int t = threadIdx.x;
  {
    const int r = t >> 2;            // e-local
    const int c0 = (t & 3) * 16;     // h
    const float* src = W + (size_t)(eb * 64 + r) * 64 + c0;
#pragma unroll
    for (int i = 0; i < 16; ++i) tile[r][c0 + i] = src[i];
  }
  __syncthreads();
  {
    const int h = t >> 2;
    const int e0 = (t & 3) * 16;
    unsigned int w[8];
#pragma unroll
    for (int i = 0; i < 8; ++i)
      w[i] = pk2(tile[e0 + 2 * i][h], tile[e0 + 2 * i + 1][h]);
    unsigned short* dst = wt3 + (size_t)(m * 64 + h) * EE + eb * 64 + e0;
    ((uint4_a*)dst)[0] = make_uint4(w[0], w[1], w[2], w[3]);
    ((uint4_a*)(dst + 8))[0] = make_uint4(w[4], w[5], w[6], w[7]);
  }
}

// ---------------------------------------------------------------------------
// Kernel 2: projections. 512 blocks x 256 thr; block = 64 rows x 192 cols.
// m201-style pipeline: k-chunk 32, triple-buffered LDS (3 x 20KB: A fp32
// 8KB swizzled + B bf16 12KB frag-contig), ALL global loads via
// global_load_lds (exactly 5/wave/chunk -> deterministic vmcnt), stage(c+2)
// issued in chunk c, raw s_barrier with s_waitcnt vmcnt(5) so one full
// stage stays in flight across the barrier. A LDS is XOR-swizzled
// (granule' = granule ^ (row&7)) via pre-swizzled per-lane SOURCE address
// (GLDS dest must stay linear); reads apply the same XOR -> conflict-free.
// Q pre-scaled by 0.125*log2(e) so attn uses exp2 (bare v_exp_f32).
// ---------------------------------------------------------------------------
__global__ __launch_bounds__(256) void proj_kernel(
    const float* __restrict__ x, const unsigned short* __restrict__ wt3,
    unsigned short* __restrict__ kws, unsigned short* __restrict__ qws,
    unsigned short* __restrict__ vtws) {
  // [buf][0..8191]   : A chunk, 64 rows x 32 fp32 (128B/row), swizzled
  // [buf][8192..20479]: B chunk, 12 frags x 1KB (frag j = cols j*16..+15)
  __shared__ __align__(16) unsigned char LB[3][20480];
  const int t = threadIdx.x;
  const int wv = t >> 6, lane = t & 63;
  const int l16 = lane & 15, quad = lane >> 4;
  const int mshalf = wv & 1;        // row half (32 rows)
  const int jbase = (wv >> 1) * 6;  // col-tile group (6 of 12)
  const size_t row0 = (size_t)blockIdx.x * 64;

  floatx4 acc[6][2];
#pragma unroll
  for (int j = 0; j < 6; ++j)
#pragma unroll
    for (int m2 = 0; m2 < 2; ++m2) acc[j][m2] = fzero();

  // A stage source pre-swizzle: LDS linear slot (row, g') must hold global
  // granule g = g' ^ (row&7). Stage instr q covers rows 8q..8q+7:
  // lane l -> row = 8q + (l>>3), LDS granule l&7, so src granule:
  const int sg = (lane & 7) ^ ((lane >> 3) & 7);
  const int arow = lane >> 3;  // row within the 8-row group of one A stage

  // 20 GLDS per block-chunk = 5 per wave: q = wv*5+i; q<8 -> A, else B j=q-8
#define STAGE(bufp, cc)                                                        \
  {                                                                            \
    _Pragma("unroll") for (int i = 0; i < 5; ++i) {                            \
      const int q = wv * 5 + i;                                                \
      if (q < 8) {                                                             \
        const float* gp =                                                      \
            x + (row0 + 8 * q + arow) * EE + (cc) * 32 + sg * 4;               \
        GLDS(gp, (bufp) + q * 1024);                                           \
      } else {                                                                 \
        const int j = q - 8;                                                   \
        const unsigned short* gp =                                             \
            wt3 + (size_t)(j * 16 + l16) * EE + (cc) * 32 + quad * 8;          \
        GLDS(gp, (bufp) + 8192 + j * 1024);                                    \
      }                                                                        \
    }                                                                          \
  }

  STAGE(&LB[0][0], 0);
  STAGE(&LB[1][0], 1);
  asm volatile("s_waitcnt vmcnt(5)" ::: "memory");  // stage(0) complete
  __builtin_amdgcn_s_barrier();
  __builtin_amdgcn_sched_barrier(0);

  int cur = 0;
  for (int c = 0; c < 32; ++c) {
    const unsigned char* Ab = &LB[cur][0];
    // A frags: row = mshalf*32 + m2*16 + l16, k floats quad*8 + h*4 (+0..3)
    float4 a4[2][2];
#pragma unroll
    for (int m2 = 0; m2 < 2; ++m2) {
      const int row = mshalf * 32 + m2 * 16 + l16;
#pragma unroll
      for (int h = 0; h < 2; ++h) {
        const int gsw = (quad * 2 + h) ^ (row & 7);
        a4[m2][h] = *(const float4_a*)(Ab + row * 128 + gsw * 16);
      }
    }
    // stage chunk c+2 into the buffer freed by chunk c-1
    if (c + 2 < 32) {
      int sb = cur + 2;
      if (sb >= 3) sb -= 3;
      STAGE(&LB[sb][0], c + 2);
    }
    short8 af[2];
#pragma unroll
    for (int m2 = 0; m2 < 2; ++m2) af[m2] = pack8(a4[m2][0], a4[m2][1]);
#pragma unroll
    for (int jj = 0; jj < 6; ++jj) {
      short8 bfv = *(const short8_a*)(Ab + 8192 + (size_t)(jbase + jj) * 1024 +
                                      lane * 16);
#pragma unroll
      for (int m2 = 0; m2 < 2; ++m2)
        acc[jj][m2] = mfma_bf16(af[m2], bfv, acc[jj][m2]);
    }
    if (c < 31) {
      if (c <= 29) {
        // newest 5 outstanding = stage(c+2); everything older (incl.
        // stage(c+1), needed next chunk) is complete.
        asm volatile("s_waitcnt vmcnt(5)" ::: "memory");
      } else {
        asm volatile("s_waitcnt vmcnt(0)" ::: "memory");
      }
      __builtin_amdgcn_s_barrier();
      __builtin_amdgcn_sched_barrier(0);
    }
    cur = (cur == 2) ? 0 : cur + 1;
  }
#undef STAGE

  const int b = (int)(row0 >> 12);
  const int tt0 = (int)(row0 & (TT - 1));
#pragma unroll
  for (int j = 0; j < 6; ++j) {
    const int jg = jbase + j;
    const int m = jg >> 2;
    const int h0 = (jg & 3) * 16;
#pragma unroll
    for (int m2 = 0; m2 < 2; ++m2) {
      floatx4 a = acc[j][m2];
      const int rbase = mshalf * 32 + m2 * 16 + quad * 4;
      if (m == 0) {
#pragma unroll
        for (int r = 0; r < 4; ++r)
          kws[(row0 + rbase + r) * HH + h0 + l16] = f2bf(a[r]);
      } else if (m == 1) {
        // 0.125 (1/sqrt(H)) * log2(e): attn does p = 2^s
#pragma unroll
        for (int r = 0; r < 4; ++r)
          qws[(row0 + rbase + r) * HH + h0 + l16] = f2bf(a[r] * 0.18033688011112042f);
      } else {  // v transposed [B,64,T]
        uint2 p;
        p.x = pk2(a[0], a[1]);
        p.y = pk2(a[2], a[3]);
        ((uint2_a*)&vtws[(size_t)(b * 64 + h0 + l16) * TT + tt0 + rbase])[0] = p;
      }
    }
  }
}

// ---------------------------------------------------------------------------
// Kernel 3: flash attention. Templated:
//  SPLIT=1: block=(b,jq,split); cid in [0,160) enumerates (jq,s), S(jq)=
//    jq/16+1 splits of key-tile range [0,jq]; 8..17 iters/block, 1280 blocks.
//    Writes partial fp32 (o,l) to slot blockIdx.x; comb_kernel finishes.
//  SPLIT=0 (ws fallback, == verified R5): 512 blocks, paired jq mapping,
//    full key range, in-kernel normalize, direct out write.
// Fixed-reference softmax: p = 2^s (q pre-scaled by 0.125*log2e), masked
// lanes 2^(-1e30) = 0. id = b + 8*cid keeps batch b on XCD b (L2 locality).
// ---------------------------------------------------------------------------
template <bool SPLIT>
__global__ __launch_bounds__(256) void attn_kernel(
    const unsigned short* __restrict__ kws, const unsigned short* __restrict__ qws,
    const unsigned short* __restrict__ vtws, float* __restrict__ dst) {
  __shared__ unsigned short KV[2][16][512];  // 32 KB dbuf
  __shared__ unsigned short pb[4][16][72];   // per-wave P, +8 pad
  const int t = threadIdx.x;
  const int wv = t >> 6, lane = t & 63;
  const int l16 = lane & 15, quad = lane >> 4;
  const int id = (int)blockIdx.x;
  int b, jq, kt0, kt1;
  if (SPLIT) {
    b = id & 7;
    const int cid = id >> 3;  // 0..159
    int s, S;
    if (cid < 16) {
      jq = cid; s = 0; S = 1;
    } else if (cid < 48) {
      const int u = cid - 16; jq = 16 + (u >> 1); s = u & 1; S = 2;
    } else if (cid < 96) {
      const int u = cid - 48; const int d = u / 3; jq = 32 + d; s = u - 3 * d; S = 3;
    } else {
      const int u = cid - 96; jq = 48 + (u >> 2); s = u & 3; S = 4;
    }
    const int n = jq + 1;
    kt0 = (s * n) / S;
    kt1 = ((s + 1) * n) / S;
  } else {
    const int r255 = id & 255;
    b = r255 & 7;
    const int m = r255 >> 3;  // 0..31
    jq = (id < 256) ? m : 63 - m;
    kt0 = 0;
    kt1 = jq + 1;
  }
  const int q0 = jq * 64;
  const int qrow = q0 + wv * 16 + l16;

  const unsigned short* qp = qws + ((size_t)b * TT + qrow) * HH + quad * 8;
  short8 qa0 = *(const short8_a*)(qp);
  short8 qa1 = *(const short8_a*)(qp + 32);

  floatx4 o[4];
#pragma unroll
  for (int nt = 0; nt < 4; ++nt) o[nt] = fzero();
  float lsum = 0.f;

#define STAGE_KV(buf, ks)                                                      \
  {                                                                            \
    _Pragma("unroll") for (int i = 0; i < 4; ++i) {                            \
      const int idx = wv * 4 + i;                                              \
      const unsigned short* gp;                                                \
      if (idx < 8) {                                                           \
        const int nt = idx >> 1, f = idx & 1;                                  \
        gp = kws + ((size_t)b * TT + (ks) + nt * 16 + l16) * HH + f * 32 +     \
             quad * 8;                                                         \
      } else {                                                                 \
        const int nt = (idx - 8) >> 1, f = idx & 1;                            \
        gp = vtws + ((size_t)(b * 64 + nt * 16 + l16)) * TT + (ks) + f * 32 +  \
             quad * 8;                                                         \
      }                                                                        \
      GLDS(gp, &KV[buf][idx][0]);                                              \
    }                                                                          \
  }

  STAGE_KV(0, kt0 * 64);
  __syncthreads();

  for (int kt = kt0; kt < kt1; ++kt) {
    const int cur = (kt - kt0) & 1;
    const int ks = kt * 64;
    if (kt + 1 < kt1) STAGE_KV(cur ^ 1, ks + 64);

    floatx4 sc[4];
#pragma unroll
    for (int nt = 0; nt < 4; ++nt) {
      short8 kf0 = *(const short8_a*)&KV[cur][nt * 2][lane * 8];
      short8 kf1 = *(const short8_a*)&KV[cur][nt * 2 + 1][lane * 8];
      floatx4 z = fzero();
      z = mfma_bf16(kf0, qa0, z);
      z = mfma_bf16(kf1, qa1, z);
      sc[nt] = z;
    }
    if (kt == jq) {  // causal mask on diagonal tile -> exp2 gives exact 0
#pragma unroll
      for (int nt = 0; nt < 4; ++nt)
#pragma unroll
        for (int r = 0; r < 4; ++r) {
          const int key = ks + nt * 16 + quad * 4 + r;
          if (key > qrow) sc[nt][r] = -1e30f;
        }
    }
    // fixed-reference softmax: p = 2^s (s already in log2 domain)
#pragma unroll
    for (int nt = 0; nt < 4; ++nt) {
      const float p0 = exp2f(sc[nt][0]);
      const float p1 = exp2f(sc[nt][1]);
      const float p2 = exp2f(sc[nt][2]);
      const float p3 = exp2f(sc[nt][3]);
      lsum += (p0 + p1) + (p2 + p3);
      uint2 pw;
      pw.x = pk2(p0, p1);
      pw.y = pk2(p2, p3);
      ((uint2_a*)&pb[wv][l16][nt * 16 + quad * 4])[0] = pw;
    }
    // P frags (same-wave LDS RAW; lgkmcnt handles)
    short8 pf0 = *(const short8_a*)&pb[wv][l16][quad * 8];
    short8 pf1 = *(const short8_a*)&pb[wv][l16][quad * 8 + 32];
#pragma unroll
    for (int nt = 0; nt < 4; ++nt) {
      short8 vf0 = *(const short8_a*)&KV[cur][8 + nt * 2][lane * 8];
      short8 vf1 = *(const short8_a*)&KV[cur][8 + nt * 2 + 1][lane * 8];
      o[nt] = mfma_bf16(vf0, pf0, o[nt]);
      o[nt] = mfma_bf16(vf1, pf1, o[nt]);
    }
    __syncthreads();
  }
#undef STAGE_KV

  // l over the 4 quads of this query column
  float lr = lsum;
  lr += __shfl_xor(lr, 16);
  lr += __shfl_xor(lr, 32);

  if (SPLIT) {
    float* op = dst + (size_t)id * SLOTF;
    const int ql = wv * 16 + l16;
#pragma unroll
    for (int nt = 0; nt < 4; ++nt) {
      float4 st;
      st.x = o[nt][0];
      st.y = o[nt][1];
      st.z = o[nt][2];
      st.w = o[nt][3];
      *(float4_a*)&op[(size_t)ql * 64 + nt * 16 + quad * 4] = st;
    }
    if (lane < 16) op[4096 + wv * 16 + lane] = lr;
  } else {
    const float inv = 1.0f / lr;
#pragma unroll
    for (int nt = 0; nt < 4; ++nt) {
      float4 st;
      st.x = o[nt][0] * inv;
      st.y = o[nt][1] * inv;
      st.z = o[nt][2] * inv;
      st.w = o[nt][3] * inv;
      *(float4_a*)&dst[((size_t)b * TT + qrow) * HH + nt * 16 + quad * 4] = st;
    }
  }
}

// ---------------------------------------------------------------------------
// Kernel 4 (split path): combine partials. 512 blocks = (b, jq); sums S(jq)
// slots of (o, l), writes out = o_sum / l_sum. Slots written by same-b attn
// blocks live on the same XCD (id = b mod 8) -> mostly L2 reads.
// ---------------------------------------------------------------------------
__global__ __launch_bounds__(256) void comb_kernel(
    const float* __restrict__ part, float* __restrict__ out) {
  const int id = (int)blockIdx.x;
  const int b = id & 7;
  const int jq = id >> 3;  // 0..63
  const int tq = jq >> 4;
  const int S = tq + 1;
  const int P = 8 * tq * (tq + 1) + (jq & 15) * S;  // prefix of (jq,0) in cid space
  const int t = threadIdx.x;
  const int r0 = t >> 6;   // 0..3
  const int h = t & 63;
  const float* s0 = part + (size_t)(b + 8 * P) * SLOTF;
  const size_t sstr = (size_t)8 * SLOTF;  // slot stride between consecutive s

#pragma unroll 4
  for (int i = 0; i < 16; ++i) {
    const int r = i * 4 + r0;
    float acc = 0.f, l = 0.f;
    for (int s2 = 0; s2 < S; ++s2) {
      acc += s0[(size_t)s2 * sstr + (size_t)r * 64 + h];
      l += s0[(size_t)s2 * sstr + 4096 + r];
    }
    out[((size_t)b * TT + jq * 64 + r) * HH + h] = acc / l;
  }
}

// ---------------------------------------------------------------------------
extern "C" void kernel_launch(void* const* d_in, const int* in_sizes, int n_in,
                              void* d_out, int out_size, void* d_ws, size_t ws_size,
                              hipStream_t stream) {
  const float* x = (const float*)d_in[0];
  const float* Wk = (const float*)d_in[1];
  const float* Wq = (const float*)d_in[2];
  const float* Wv = (const float*)d_in[3];
  float* out = (float*)d_out;

  // ws layout: k bf16 [B,T,64] | q bf16 [B,T,64] | vT bf16 [B,64,T] |
  //            wt3 bf16 [3,64,1024] | partials fp32 [1280][4160] (if room)
  unsigned short* kws = (unsigned short*)d_ws;
  unsigned short* qws = kws + (size_t)BB * TT * HH;
  unsigned short* vtws = qws + (size_t)BB * TT * HH;
  unsigned short* wt3 = vtws + (size_t)BB * TT * HH;
  float* part = (float*)(wt3 + (size_t)3 * HH * EE);

  const size_t base_bytes = (size_t)3 * BB * TT * HH * 2 + (size_t)3 * HH * EE * 2;
  const size_t need = base_bytes + (size_t)BB * NSLOT * SLOTF * 4;
  const bool use_split = (ws_size >= need);

  hipLaunchKernelGGL(wt_kernel, dim3(16, 3), dim3(256), 0, stream, Wk, Wq, Wv, wt3);
  hipLaunchKernelGGL(proj_kernel, dim3(512), dim3(256), 0, stream, x, wt3, kws, qws,
                     vtws);
  if (use_split) {
    hipLaunchKernelGGL((attn_kernel<true>), dim3(BB * NSLOT), dim3(256), 0, stream,
                       kws, qws, vtws, part);
    hipLaunchKernelGGL(comb_kernel, dim3(512), dim3(256), 0, stream, part, out);
  } else {
    hipLaunchKernelGGL((attn_kernel<false>), dim3(512), dim3(256), 0, stream,
                       kws, qws, vtws, out);
  }
}